// Round 5
// baseline (360.143 us; speedup 1.0000x reference)
//
#include <hip/hip_runtime.h>

typedef unsigned int uint32;
typedef unsigned short u16t;

// ============================================================
// Compile-time reproduction of np.random.RandomState(0).randn
// (MT19937 + polar Box-Muller). Exact integer/IEEE-double control
// flow -> constexpr-safe; only log/sqrt evaluated on device.
// ============================================================
struct MTS { unsigned int mt[624]; int mti; };

constexpr unsigned int mt_next(MTS& s){
  if (s.mti >= 624){
    for (int i = 0; i < 624; i++){
      unsigned int y = (s.mt[i] & 0x80000000u) | (s.mt[(i+1)%624] & 0x7fffffffu);
      unsigned int v = s.mt[(i+397)%624] ^ (y >> 1);
      if (y & 1u) v ^= 2567483615u;
      s.mt[i] = v;
    }
    s.mti = 0;
  }
  unsigned int y = s.mt[s.mti]; s.mti++;
  y ^= y >> 11;
  y ^= (y << 7)  & 2636928640u;
  y ^= (y << 15) & 4022730752u;
  y ^= y >> 18;
  return y;
}
constexpr double mt_dbl(MTS& s){
  unsigned int a = mt_next(s) >> 5;
  unsigned int b = mt_next(s) >> 6;
  return ((double)a * 67108864.0 + (double)b) / 9007199254740992.0;
}

constexpr int NPAIR = 308;
struct GenData {
  double r2[NPAIR], x1[NPAIR], x2[NPAIR];
  int g_of_t[729];
};

constexpr GenData make_gen(){
  GenData g{};
  for (int i = 0; i < 729; i++) g.g_of_t[i] = -1;
  MTS s{};
  {
    unsigned int sd = 0u;
    for (int p = 0; p < 624; p++){
      s.mt[p] = sd;
      sd = 1812433253u * (sd ^ (sd >> 30)) + (unsigned)p + 1u;
    }
    s.mti = 624;
  }
  for (int p = 0; p < NPAIR; p++){
    double a = 0.0, b = 0.0, r = 0.0;
    do {
      a = 2.0 * mt_dbl(s) - 1.0;
      b = 2.0 * mt_dbl(s) - 1.0;
      r = a*a + b*b;
    } while (r >= 1.0 || r == 0.0);
    g.r2[p] = r; g.x1[p] = a; g.x2[p] = b;
  }
  const int L1[15] = {0,0,0,1,1,1,1,1,1,2,2,2,2,2,2};
  const int L2[15] = {0,1,2,0,1,1,1,2,2,0,1,1,2,2,2};
  const int L3[15] = {0,1,2,1,0,1,2,1,2,2,1,2,0,1,2};
  const int OFF[3] = {0,1,4};
  int gi = 0;
  for (int p = 0; p < 15; p++){
    int d1 = 2*L1[p]+1, d2 = 2*L2[p]+1, d3 = 2*L3[p]+1;
    for (int i = 0; i < d1; i++)
      for (int j = 0; j < d2; j++)
        for (int k = 0; k < d3; k++)
          g.g_of_t[(OFF[L1[p]]+i)*81 + (OFF[L2[p]]+j)*9 + (OFF[L3[p]]+k)] = gi++;
  }
  return g;
}

constexpr GenData h_gd = make_gen();
__constant__ GenData c_gd = h_gd;

__global__ void gen_T_kernel(float* __restrict__ T){
  int t = blockIdx.x * blockDim.x + threadIdx.x;
  if (t >= 729) return;
  int gi = c_gd.g_of_t[t];
  float v = 0.f;
  if (gi >= 0){
    int p = gi >> 1;
    double r2 = c_gd.r2[p];
    double f  = sqrt(-2.0 * log(r2) / r2);
    double xx = (gi & 1) ? c_gd.x1[p] : c_gd.x2[p];
    v = (float)((f * xx) / 3.0);
  }
  T[t] = v;
}

// ---- fp32 -> bf16 (RNE) ----
__device__ __forceinline__ u16t f2b(float f){
  uint32 u = __float_as_uint(f);
  u += 0x7fffu + ((u >> 16) & 1u);
  return (u16t)(u >> 16);
}

// x -> bf16, 4 elements per thread
__global__ __launch_bounds__(256) void x2b_kernel(const float* __restrict__ x,
                                                  u16t* __restrict__ xb, int n4){
  int i = blockIdx.x * 256 + threadIdx.x;
  if (i >= n4) return;
  const float4 v = *reinterpret_cast<const float4*>(x + (size_t)i * 4);
  uint32 a = (uint32)f2b(v.x) | ((uint32)f2b(v.y) << 16);
  uint32 b = (uint32)f2b(v.z) | ((uint32)f2b(v.w) << 16);
  reinterpret_cast<uint2*>(xb)[i] = make_uint2(a, b);
}

// ============================================================
// CSR-by-dst: hist -> scan -> fillW (W per slot, f32)
// ============================================================
__global__ __launch_bounds__(256) void hist_kernel(const int* __restrict__ dst,
                                                   int* __restrict__ cnt,
                                                   int* __restrict__ pos, int E){
  int e = blockIdx.x * 256 + threadIdx.x;
  if (e < E) pos[e] = atomicAdd(&cnt[dst[e]], 1);
}

__global__ void scan_kernel(const int* __restrict__ cnt, int* __restrict__ start, int n){
  __shared__ int part[1024];
  int t = threadIdx.x;
  int ch = (n + 1023) >> 10;
  int b0 = t * ch;
  int sum = 0;
  for (int j = 0; j < ch; j++){ int i = b0 + j; if (i < n) sum += cnt[i]; }
  part[t] = sum;
  __syncthreads();
  for (int off = 1; off < 1024; off <<= 1){
    int v = 0;
    if (t >= off) v = part[t - off];
    __syncthreads();
    part[t] += v;
    __syncthreads();
  }
  int run = (t > 0) ? part[t-1] : 0;
  for (int j = 0; j < ch; j++){
    int i = b0 + j;
    if (i < n){ start[i] = run; run += cnt[i]; }
  }
  if (t == 1023) start[n] = part[1023];
}

// ONE EDGE PER WAVE (parallel): W[81] = sh . T, stored f32 at CSR
// slot (84-float row = 336B), plus esrc[p] = src.
__global__ __launch_bounds__(256) void fillW_kernel(
    const int* __restrict__ dst, const int* __restrict__ src,
    const float* __restrict__ sh, const int* __restrict__ start,
    const int* __restrict__ pos, const float* __restrict__ Tg,
    int* __restrict__ esrc, float* __restrict__ Wr, int E)
{
  const int e = blockIdx.x * 4 + (threadIdx.x >> 6);
  const int lane = threadIdx.x & 63;
  if (e >= E) return;

  const int i0 = lane / 9, k0 = lane % 9;
  const bool has1 = (lane < 17);
  const int e1 = has1 ? (64 + lane) : 63;
  const int i1 = e1 / 9, k1 = e1 % 9;
  float t0[9], t1[9];
#pragma unroll
  for (int j = 0; j < 9; j++){
    t0[j] = Tg[i0*81 + j*9 + k0];
    t1[j] = Tg[i1*81 + j*9 + k1];
  }

  const int p = start[dst[e]] + pos[e];
  if (lane == 0) esrc[p] = src[e];

  const float* s9 = sh + (size_t)e * 9;
  float sv[9];
#pragma unroll
  for (int j = 0; j < 9; j++) sv[j] = s9[j];

  float w0 = 0.f, w1 = 0.f;
#pragma unroll
  for (int j = 0; j < 9; j++){ w0 = fmaf(sv[j], t0[j], w0); w1 = fmaf(sv[j], t1[j], w1); }

  float* wrow = Wr + (size_t)p * 84;
  wrow[lane] = w0;
  if (has1) wrow[64 + lane] = w1;
}

// ============================================================
// Main TP kernel: wave per node, lane = channel. W read as f32
// via uniform-address float4 loads (L1/L2 broadcast, vmcnt
// pipelined by compiler). esrc and x software-pipelined 1 deep.
// ============================================================
__global__ __launch_bounds__(256) void tp_csr_vW(
    const u16t* __restrict__ xg, const int* __restrict__ esrc,
    const int* __restrict__ starts, const float* __restrict__ Wr,
    float* __restrict__ out, int n_nodes)
{
  const int wv = threadIdx.x >> 6;
  const int lane = threadIdx.x & 63;
  const int node = blockIdx.x * 4 + wv;
  if (node >= n_nodes) return;

  float acc[9];
#pragma unroll
  for (int k = 0; k < 9; k++) acc[k] = 0.f;

  const int s0 = __builtin_amdgcn_readfirstlane(starts[node]);
  const int s1 = __builtin_amdgcn_readfirstlane(starts[node + 1]);

  if (s0 < s1){
    int sn_c = __builtin_amdgcn_readfirstlane(esrc[s0]);
    float xcur[9];
    {
      const u16t* xr = xg + (size_t)sn_c * 576;
      xcur[0] = __uint_as_float((uint32)xr[lane] << 16);
#pragma unroll
      for (int t = 0; t < 3; t++) xcur[1 + t] = __uint_as_float((uint32)xr[64 + 3*lane + t] << 16);
#pragma unroll
      for (int t = 0; t < 5; t++) xcur[4 + t] = __uint_as_float((uint32)xr[256 + 5*lane + t] << 16);
    }
    int sn_n = __builtin_amdgcn_readfirstlane(esrc[(s0 + 1 < s1) ? (s0 + 1) : s0]);

    for (int idx = s0; idx < s1; ++idx){
      // ---- W row for current edge: 21 uniform-address vector loads
      const float* wrow = Wr + (size_t)idx * 84;
      float4 W4[20];
#pragma unroll
      for (int q = 0; q < 20; q++) W4[q] = reinterpret_cast<const float4*>(wrow)[q];
      const float w80 = wrow[80];

      // ---- prefetch next edge's x (clamped; overlaps this edge's compute)
      float xnxt[9];
      {
        const u16t* xr = xg + (size_t)sn_n * 576;
        xnxt[0] = __uint_as_float((uint32)xr[lane] << 16);
#pragma unroll
        for (int t = 0; t < 3; t++) xnxt[1 + t] = __uint_as_float((uint32)xr[64 + 3*lane + t] << 16);
#pragma unroll
        for (int t = 0; t < 5; t++) xnxt[4 + t] = __uint_as_float((uint32)xr[256 + 5*lane + t] << 16);
      }
      // ---- prefetch esrc two ahead (clamped)
      const int sn_n2 = __builtin_amdgcn_readfirstlane(esrc[(idx + 2 < s1) ? (idx + 2) : (s1 - 1)]);

      // ---- matvec: acc[k] += xcur[i] * W[i*9+k]
#pragma unroll
      for (int i = 0; i < 9; i++){
        const float xi = xcur[i];
#pragma unroll
        for (int k = 0; k < 9; k++){
          const int t = i*9 + k;
          const float w = (t < 80) ? reinterpret_cast<const float*>(&W4[t >> 2])[t & 3] : w80;
          acc[k] = fmaf(xi, w, acc[k]);
        }
      }

      // ---- rotate pipeline regs
#pragma unroll
      for (int j = 0; j < 9; j++) xcur[j] = xnxt[j];
      sn_n = sn_n2;
    }
  }

  float* orow = out + (size_t)node * 576;
  orow[lane] = acc[0];
#pragma unroll
  for (int t = 0; t < 3; t++) orow[64 + 3*lane + t] = acc[1 + t];
#pragma unroll
  for (int t = 0; t < 5; t++) orow[256 + 5*lane + t] = acc[4 + t];
}

// ============================================================
// Mid fallback (R3 path): fill esrc+sh_r, readlane-broadcast tp
// ============================================================
__device__ __forceinline__ float bcast_lane(float v, int lane){
  return __uint_as_float(__builtin_amdgcn_readlane(__float_as_uint(v), lane));
}

__global__ __launch_bounds__(256) void fill_kernel(const int* __restrict__ dst,
                                                   const int* __restrict__ src,
                                                   const float* __restrict__ sh,
                                                   const int* __restrict__ start,
                                                   const int* __restrict__ pos,
                                                   int* __restrict__ esrc,
                                                   float* __restrict__ sh_r, int E){
  int e = blockIdx.x * 256 + threadIdx.x;
  if (e >= E) return;
  int p = start[dst[e]] + pos[e];
  esrc[p] = src[e];
  const float* s9 = sh + (size_t)e * 9;
  float* d9 = sh_r + (size_t)p * 9;
#pragma unroll
  for (int j = 0; j < 9; j++) d9[j] = s9[j];
}

__global__ __launch_bounds__(256) void tp_csr_rl(
    const float* __restrict__ x, const float* __restrict__ sh_r,
    const int* __restrict__ esrc, const int* __restrict__ starts,
    const float* __restrict__ Tg, float* __restrict__ out, int n_nodes)
{
  const int wv = threadIdx.x >> 6;
  const int lane = threadIdx.x & 63;
  const int node = blockIdx.x * 4 + wv;
  if (node >= n_nodes) return;

  const int i0 = lane / 9, k0 = lane % 9;
  const bool has1 = (lane < 17);
  const int e1 = has1 ? (64 + lane) : 63;
  const int i1 = e1 / 9, k1 = e1 % 9;
  float t0[9], t1[9];
#pragma unroll
  for (int j = 0; j < 9; j++){
    t0[j] = Tg[i0*81 + j*9 + k0];
    t1[j] = Tg[i1*81 + j*9 + k1];
  }

  float acc[9];
#pragma unroll
  for (int k = 0; k < 9; k++) acc[k] = 0.f;

  const int s0 = starts[node];
  const int s1 = starts[node + 1];

  for (int idx = s0; idx < s1; ++idx){
    const int sn = __builtin_amdgcn_readfirstlane(esrc[idx]);
    const float* xr = x + (size_t)sn * 576;
    float xv[9];
    xv[0] = xr[lane];
#pragma unroll
    for (int t = 0; t < 3; t++) xv[1 + t] = xr[64 + 3*lane + t];
#pragma unroll
    for (int t = 0; t < 5; t++) xv[4 + t] = xr[256 + 5*lane + t];

    const float* p9 = sh_r + (size_t)idx * 9;
    float sh_c[9];
#pragma unroll
    for (int j = 0; j < 9; j++) sh_c[j] = p9[j];

    float w0 = 0.f, w1 = 0.f;
#pragma unroll
    for (int j = 0; j < 9; j++) w0 = fmaf(sh_c[j], t0[j], w0);
#pragma unroll
    for (int j = 0; j < 9; j++) w1 = fmaf(sh_c[j], t1[j], w1);

#pragma unroll
    for (int i = 0; i < 9; i++){
      const float xi = xv[i];
#pragma unroll
      for (int k = 0; k < 9; k++){
        const int t = i*9 + k;
        const float w = (t < 64) ? bcast_lane(w0, t) : bcast_lane(w1, t - 64);
        acc[k] = fmaf(xi, w, acc[k]);
      }
    }
  }

  float* orow = out + (size_t)node * 576;
  orow[lane] = acc[0];
#pragma unroll
  for (int t = 0; t < 3; t++) orow[64 + 3*lane + t] = acc[1 + t];
#pragma unroll
  for (int t = 0; t < 5; t++) orow[256 + 5*lane + t] = acc[4 + t];
}

// ============================================================
// Last-resort fallback: edge-parallel with atomics
// ============================================================
__global__ __launch_bounds__(256) void tp_edge_atomic(
    const float* __restrict__ x, const float* __restrict__ sh,
    const int* __restrict__ src, const int* __restrict__ dst,
    const float* __restrict__ Tg, float* __restrict__ out, int E)
{
  const int wv = threadIdx.x >> 6;
  const int lane = threadIdx.x & 63;
  const int e = blockIdx.x * 4 + wv;
  if (e >= E) return;

  const int i0 = lane / 9, k0 = lane % 9;
  const bool has1 = (lane < 17);
  const int e1 = has1 ? (64 + lane) : 63;
  const int i1 = e1 / 9, k1 = e1 % 9;
  float t0[9], t1[9];
#pragma unroll
  for (int j = 0; j < 9; j++){
    t0[j] = Tg[i0*81 + j*9 + k0];
    t1[j] = Tg[i1*81 + j*9 + k1];
  }

  const int sn = src[e];
  const float* she = sh + (size_t)e * 9;
  float sv[9];
#pragma unroll
  for (int j = 0; j < 9; j++) sv[j] = she[j];

  float w0 = 0.f, w1 = 0.f;
#pragma unroll
  for (int j = 0; j < 9; j++) w0 = fmaf(sv[j], t0[j], w0);
#pragma unroll
  for (int j = 0; j < 9; j++) w1 = fmaf(sv[j], t1[j], w1);

  const float* xr = x + (size_t)sn * 576;
  float xv[9];
  xv[0] = xr[lane];
#pragma unroll
  for (int t = 0; t < 3; t++) xv[1 + t] = xr[64 + 3*lane + t];
#pragma unroll
  for (int t = 0; t < 5; t++) xv[4 + t] = xr[256 + 5*lane + t];

  float o[9];
#pragma unroll
  for (int k = 0; k < 9; k++) o[k] = 0.f;
#pragma unroll
  for (int i = 0; i < 9; i++){
    const float xi = xv[i];
#pragma unroll
    for (int k = 0; k < 9; k++){
      const int t = i*9 + k;
      const float w = (t < 64) ? bcast_lane(w0, t) : bcast_lane(w1, t - 64);
      o[k] = fmaf(xi, w, o[k]);
    }
  }

  float* orow = out + (size_t)dst[e] * 576;
  atomicAdd(&orow[lane], o[0]);
#pragma unroll
  for (int t = 0; t < 3; t++) atomicAdd(&orow[64 + 3*lane + t], o[1 + t]);
#pragma unroll
  for (int t = 0; t < 5; t++) atomicAdd(&orow[256 + 5*lane + t], o[4 + t]);
}

// ============================================================
extern "C" void kernel_launch(void* const* d_in, const int* in_sizes, int n_in,
                              void* d_out, int out_size, void* d_ws, size_t ws_size,
                              hipStream_t stream)
{
  const float* x  = (const float*)d_in[0];
  const float* sh = (const float*)d_in[1];
  const int* src  = (const int*)d_in[2];
  const int* dst  = (const int*)d_in[3];
  float* out = (float*)d_out;

  const int N = in_sizes[0] / 576;
  const int E = in_sizes[2];

  // layout (u32 units):
  // Tw[1024] | cnt[N] | strt[N+1] | pos[E] | esrc[E] | xb[288N] | Wr[84E]
  const size_t o_cnt  = 1024;
  const size_t o_strt = o_cnt + (size_t)N;
  const size_t o_pos  = o_strt + (size_t)N + 1;
  const size_t o_esrc = o_pos + (size_t)E;
  size_t o_xb   = o_esrc + (size_t)E;
  o_xb = (o_xb + 3) & ~(size_t)3;
  size_t o_Wr   = o_xb + (size_t)288 * N;
  o_Wr = (o_Wr + 3) & ~(size_t)3;              // 16B-align W rows (336B rows)
  const size_t need_big = (o_Wr + (size_t)84 * E) * 4;
  const size_t need_mid = ((size_t)1024 + N + (N + 1) + E + E + (size_t)9 * E) * 4;

  float* Tw = (float*)d_ws;
  gen_T_kernel<<<3, 256, 0, stream>>>(Tw);

  if (ws_size >= need_big){
    int* cnt    = (int*)d_ws + o_cnt;
    int* strt   = (int*)d_ws + o_strt;
    int* pos    = (int*)d_ws + o_pos;
    int* esrc   = (int*)d_ws + o_esrc;
    u16t* xb    = (u16t*)((uint32*)d_ws + o_xb);
    float* Wr   = (float*)((uint32*)d_ws + o_Wr);

    const int n4 = (int)(((size_t)N * 576) / 4);
    x2b_kernel<<<(n4 + 255) / 256, 256, 0, stream>>>(x, xb, n4);
    hipMemsetAsync(cnt, 0, (size_t)N * 4, stream);
    hist_kernel<<<(E + 255) / 256, 256, 0, stream>>>(dst, cnt, pos, E);
    scan_kernel<<<1, 1024, 0, stream>>>(cnt, strt, N);
    fillW_kernel<<<(E + 3) / 4, 256, 0, stream>>>(dst, src, sh, strt, pos, Tw, esrc, Wr, E);
    tp_csr_vW<<<(N + 3) / 4, 256, 0, stream>>>(xb, esrc, strt, Wr, out, N);
  } else if (ws_size >= need_mid){
    int* cnt    = (int*)d_ws + 1024;
    int* strt   = cnt + N;
    int* pos    = strt + N + 1;
    int* esrc   = pos + E;
    float* sh_r = (float*)(esrc + E);

    hipMemsetAsync(cnt, 0, (size_t)N * 4, stream);
    hist_kernel<<<(E + 255) / 256, 256, 0, stream>>>(dst, cnt, pos, E);
    scan_kernel<<<1, 1024, 0, stream>>>(cnt, strt, N);
    fill_kernel<<<(E + 255) / 256, 256, 0, stream>>>(dst, src, sh, strt, pos, esrc, sh_r, E);
    tp_csr_rl<<<(N + 3) / 4, 256, 0, stream>>>(x, sh_r, esrc, strt, Tw, out, N);
  } else {
    hipMemsetAsync(out, 0, (size_t)out_size * 4, stream);
    tp_edge_atomic<<<(E + 3) / 4, 256, 0, stream>>>(x, sh, src, dst, Tw, out, E);
  }
}

// Round 6
// 195.677 us; speedup vs baseline: 1.8405x; 1.8405x over previous
//
#include <hip/hip_runtime.h>

typedef unsigned int uint32;
typedef unsigned short u16t;

// ============================================================
// Compile-time reproduction of np.random.RandomState(0).randn
// (MT19937 + polar Box-Muller). Exact integer/IEEE-double control
// flow -> constexpr-safe; only log/sqrt evaluated on device.
// ============================================================
struct MTS { unsigned int mt[624]; int mti; };

constexpr unsigned int mt_next(MTS& s){
  if (s.mti >= 624){
    for (int i = 0; i < 624; i++){
      unsigned int y = (s.mt[i] & 0x80000000u) | (s.mt[(i+1)%624] & 0x7fffffffu);
      unsigned int v = s.mt[(i+397)%624] ^ (y >> 1);
      if (y & 1u) v ^= 2567483615u;
      s.mt[i] = v;
    }
    s.mti = 0;
  }
  unsigned int y = s.mt[s.mti]; s.mti++;
  y ^= y >> 11;
  y ^= (y << 7)  & 2636928640u;
  y ^= (y << 15) & 4022730752u;
  y ^= y >> 18;
  return y;
}
constexpr double mt_dbl(MTS& s){
  unsigned int a = mt_next(s) >> 5;
  unsigned int b = mt_next(s) >> 6;
  return ((double)a * 67108864.0 + (double)b) / 9007199254740992.0;
}

constexpr int NPAIR = 308;
struct GenData {
  double r2[NPAIR], x1[NPAIR], x2[NPAIR];
  int g_of_t[729];
};

constexpr GenData make_gen(){
  GenData g{};
  for (int i = 0; i < 729; i++) g.g_of_t[i] = -1;
  MTS s{};
  {
    unsigned int sd = 0u;
    for (int p = 0; p < 624; p++){
      s.mt[p] = sd;
      sd = 1812433253u * (sd ^ (sd >> 30)) + (unsigned)p + 1u;
    }
    s.mti = 624;
  }
  for (int p = 0; p < NPAIR; p++){
    double a = 0.0, b = 0.0, r = 0.0;
    do {
      a = 2.0 * mt_dbl(s) - 1.0;
      b = 2.0 * mt_dbl(s) - 1.0;
      r = a*a + b*b;
    } while (r >= 1.0 || r == 0.0);
    g.r2[p] = r; g.x1[p] = a; g.x2[p] = b;
  }
  const int L1[15] = {0,0,0,1,1,1,1,1,1,2,2,2,2,2,2};
  const int L2[15] = {0,1,2,0,1,1,1,2,2,0,1,1,2,2,2};
  const int L3[15] = {0,1,2,1,0,1,2,1,2,2,1,2,0,1,2};
  const int OFF[3] = {0,1,4};
  int gi = 0;
  for (int p = 0; p < 15; p++){
    int d1 = 2*L1[p]+1, d2 = 2*L2[p]+1, d3 = 2*L3[p]+1;
    for (int i = 0; i < d1; i++)
      for (int j = 0; j < d2; j++)
        for (int k = 0; k < d3; k++)
          g.g_of_t[(OFF[L1[p]]+i)*81 + (OFF[L2[p]]+j)*9 + (OFF[L3[p]]+k)] = gi++;
  }
  return g;
}

constexpr GenData h_gd = make_gen();
__constant__ GenData c_gd = h_gd;

__global__ void gen_T_kernel(float* __restrict__ T){
  int t = blockIdx.x * blockDim.x + threadIdx.x;
  if (t >= 729) return;
  int gi = c_gd.g_of_t[t];
  float v = 0.f;
  if (gi >= 0){
    int p = gi >> 1;
    double r2 = c_gd.r2[p];
    double f  = sqrt(-2.0 * log(r2) / r2);
    double xx = (gi & 1) ? c_gd.x1[p] : c_gd.x2[p];
    v = (float)((f * xx) / 3.0);
  }
  T[t] = v;
}

// ---- fp32 -> bf16 (RNE) ----
__device__ __forceinline__ u16t f2b(float f){
  uint32 u = __float_as_uint(f);
  u += 0x7fffu + ((u >> 16) & 1u);
  return (u16t)(u >> 16);
}

// x -> bf16, 4 elements per thread (linear, full BW)
__global__ __launch_bounds__(256) void x2b_kernel(const float* __restrict__ x,
                                                  u16t* __restrict__ xb, int n4){
  int i = blockIdx.x * 256 + threadIdx.x;
  if (i >= n4) return;
  const float4 v = *reinterpret_cast<const float4*>(x + (size_t)i * 4);
  uint32 a = (uint32)f2b(v.x) | ((uint32)f2b(v.y) << 16);
  uint32 b = (uint32)f2b(v.z) | ((uint32)f2b(v.w) << 16);
  reinterpret_cast<uint2*>(xb)[i] = make_uint2(a, b);
}

// ============================================================
// CSR-by-dst: hist -> scan -> fill (esrc + sh rows of 12 floats)
// ============================================================
__global__ __launch_bounds__(256) void hist_kernel(const int* __restrict__ dst,
                                                   int* __restrict__ cnt,
                                                   int* __restrict__ pos, int E){
  int e = blockIdx.x * 256 + threadIdx.x;
  if (e < E) pos[e] = atomicAdd(&cnt[dst[e]], 1);
}

__global__ void scan_kernel(const int* __restrict__ cnt, int* __restrict__ start, int n){
  __shared__ int part[1024];
  int t = threadIdx.x;
  int ch = (n + 1023) >> 10;
  int b0 = t * ch;
  int sum = 0;
  for (int j = 0; j < ch; j++){ int i = b0 + j; if (i < n) sum += cnt[i]; }
  part[t] = sum;
  __syncthreads();
  for (int off = 1; off < 1024; off <<= 1){
    int v = 0;
    if (t >= off) v = part[t - off];
    __syncthreads();
    part[t] += v;
    __syncthreads();
  }
  int run = (t > 0) ? part[t-1] : 0;
  for (int j = 0; j < ch; j++){
    int i = b0 + j;
    if (i < n){ start[i] = run; run += cnt[i]; }
  }
  if (t == 1023) start[n] = part[1023];
}

// esrc[p]=src[e]; sh_r row p (12-float stride, 16B aligned) = sh[e]
__global__ __launch_bounds__(256) void fill_kernel(const int* __restrict__ dst,
                                                   const int* __restrict__ src,
                                                   const float* __restrict__ sh,
                                                   const int* __restrict__ start,
                                                   const int* __restrict__ pos,
                                                   int* __restrict__ esrc,
                                                   float* __restrict__ sh_r, int E){
  int e = blockIdx.x * 256 + threadIdx.x;
  if (e >= E) return;
  int p = start[dst[e]] + pos[e];
  esrc[p] = src[e];
  const float* s9 = sh + (size_t)e * 9;
  float* d12 = sh_r + (size_t)p * 12;
#pragma unroll
  for (int j = 0; j < 9; j++) d12[j] = s9[j];
}

// ============================================================
// Fused TP kernel: one wave per node, lane = channel (64).
// Per edge:
//   - x row (bf16) loads issued first, latency hides under build
//   - W[81] = sh . T built in registers (T per-lane constant)
//   - W broadcast via flat LDS: 2 writes + 21 ds_read_b128,
//     all lanes same address -> broadcast, zero bank conflicts
//   - 81-FMA matvec, node row accumulated in registers
// ============================================================
__global__ __launch_bounds__(256) void tp_fused(
    const u16t* __restrict__ xg, const float* __restrict__ sh_r,
    const int* __restrict__ esrc, const int* __restrict__ starts,
    const float* __restrict__ Tg, float* __restrict__ out, int n_nodes)
{
  __shared__ __align__(16) float Wl[4][88];   // flat 81 (+pad), 16B-aligned rows

  const int wv = threadIdx.x >> 6;
  const int lane = threadIdx.x & 63;
  const int node = blockIdx.x * 4 + wv;
  if (node >= n_nodes) return;

  // per-lane constant T fragments (entry t = i*9+k; lane owns t=lane, t=64+lane)
  const int i0 = lane / 9, k0 = lane % 9;
  const bool has1 = (lane < 17);
  const int e1 = has1 ? (64 + lane) : 63;
  const int i1 = e1 / 9, k1 = e1 % 9;
  float t0[9], t1[9];
#pragma unroll
  for (int j = 0; j < 9; j++){
    t0[j] = Tg[i0*81 + j*9 + k0];
    t1[j] = Tg[i1*81 + j*9 + k1];
  }

  // loop-invariant x element offsets for this lane
  const int off0 = lane;
  const int off1 = 64 + 3*lane;
  const int off2 = 256 + 5*lane;

  float acc[9];
#pragma unroll
  for (int k = 0; k < 9; k++) acc[k] = 0.f;

  const int s0 = __builtin_amdgcn_readfirstlane(starts[node]);
  const int s1 = __builtin_amdgcn_readfirstlane(starts[node + 1]);
  float* Wp = Wl[wv];

  if (s0 < s1){
    // prologue: first edge's sn + sh
    int sn_c = __builtin_amdgcn_readfirstlane(esrc[s0]);
    float4 shA, shB; float sh8;
    {
      const float* p12 = sh_r + (size_t)s0 * 12;
      shA = reinterpret_cast<const float4*>(p12)[0];
      shB = reinterpret_cast<const float4*>(p12)[1];
      sh8 = p12[8];
    }

    for (int idx = s0; idx < s1; ++idx){
      // ---- issue current edge's x loads (bf16), latency hides under build
      const u16t* xr = xg + (size_t)sn_c * 576;
      u16t xraw[9];
      xraw[0] = xr[off0];
#pragma unroll
      for (int t = 0; t < 3; t++) xraw[1 + t] = xr[off1 + t];
#pragma unroll
      for (int t = 0; t < 5; t++) xraw[4 + t] = xr[off2 + t];

      // ---- prefetch next edge's sn + sh (breaks serial dependence)
      const int nidx = (idx + 1 < s1) ? (idx + 1) : idx;
      const int sn_n = __builtin_amdgcn_readfirstlane(esrc[nidx]);
      float4 shAn, shBn; float sh8n;
      {
        const float* p12 = sh_r + (size_t)nidx * 12;
        shAn = reinterpret_cast<const float4*>(p12)[0];
        shBn = reinterpret_cast<const float4*>(p12)[1];
        sh8n = p12[8];
      }

      // ---- W build in registers
      const float sv[9] = {shA.x, shA.y, shA.z, shA.w, shB.x, shB.y, shB.z, shB.w, sh8};
      float w0 = 0.f, w1 = 0.f;
#pragma unroll
      for (int j = 0; j < 9; j++){ w0 = fmaf(sv[j], t0[j], w0); w1 = fmaf(sv[j], t1[j], w1); }

      // ---- broadcast via flat LDS
      Wp[lane] = w0;
      if (has1) Wp[64 + lane] = w1;
      asm volatile("s_waitcnt lgkmcnt(0)" ::: "memory");  // writes visible wave-wide

      // ---- unpack x (bf16 -> f32)
      float xv[9];
#pragma unroll
      for (int t = 0; t < 9; t++) xv[t] = __uint_as_float((uint32)xraw[t] << 16);

      // ---- matvec: acc[k] += xv[i] * W[i*9+k]  (21 broadcast b128 reads)
      float4 W4[21];
#pragma unroll
      for (int q = 0; q < 21; q++) W4[q] = reinterpret_cast<const float4*>(Wp)[q];
#pragma unroll
      for (int i = 0; i < 9; i++){
        const float xi = xv[i];
#pragma unroll
        for (int k = 0; k < 9; k++){
          const int t = i*9 + k;
          const float w = reinterpret_cast<const float*>(&W4[t >> 2])[t & 3];
          acc[k] = fmaf(xi, w, acc[k]);
        }
      }
      asm volatile("" ::: "memory");  // next iter's LDS writes stay after these reads

      // ---- rotate pipeline regs
      sn_c = sn_n; shA = shAn; shB = shBn; sh8 = sh8n;
    }
  }

  float* orow = out + (size_t)node * 576;
  orow[off0] = acc[0];
#pragma unroll
  for (int t = 0; t < 3; t++) orow[off1 + t] = acc[1 + t];
#pragma unroll
  for (int t = 0; t < 5; t++) orow[off2 + t] = acc[4 + t];
}

// ============================================================
// Last-resort fallback: edge-parallel with atomics (readlane bcast)
// ============================================================
__device__ __forceinline__ float bcast_lane(float v, int lane){
  return __uint_as_float(__builtin_amdgcn_readlane(__float_as_uint(v), lane));
}

__global__ __launch_bounds__(256) void tp_edge_atomic(
    const float* __restrict__ x, const float* __restrict__ sh,
    const int* __restrict__ src, const int* __restrict__ dst,
    const float* __restrict__ Tg, float* __restrict__ out, int E)
{
  const int wv = threadIdx.x >> 6;
  const int lane = threadIdx.x & 63;
  const int e = blockIdx.x * 4 + wv;
  if (e >= E) return;

  const int i0 = lane / 9, k0 = lane % 9;
  const bool has1 = (lane < 17);
  const int e1 = has1 ? (64 + lane) : 63;
  const int i1 = e1 / 9, k1 = e1 % 9;
  float t0[9], t1[9];
#pragma unroll
  for (int j = 0; j < 9; j++){
    t0[j] = Tg[i0*81 + j*9 + k0];
    t1[j] = Tg[i1*81 + j*9 + k1];
  }

  const int sn = src[e];
  const float* she = sh + (size_t)e * 9;
  float sv[9];
#pragma unroll
  for (int j = 0; j < 9; j++) sv[j] = she[j];

  float w0 = 0.f, w1 = 0.f;
#pragma unroll
  for (int j = 0; j < 9; j++) w0 = fmaf(sv[j], t0[j], w0);
#pragma unroll
  for (int j = 0; j < 9; j++) w1 = fmaf(sv[j], t1[j], w1);

  const float* xr = x + (size_t)sn * 576;
  float xv[9];
  xv[0] = xr[lane];
#pragma unroll
  for (int t = 0; t < 3; t++) xv[1 + t] = xr[64 + 3*lane + t];
#pragma unroll
  for (int t = 0; t < 5; t++) xv[4 + t] = xr[256 + 5*lane + t];

  float o[9];
#pragma unroll
  for (int k = 0; k < 9; k++) o[k] = 0.f;
#pragma unroll
  for (int i = 0; i < 9; i++){
    const float xi = xv[i];
#pragma unroll
    for (int k = 0; k < 9; k++){
      const int t = i*9 + k;
      const float w = (t < 64) ? bcast_lane(w0, t) : bcast_lane(w1, t - 64);
      o[k] = fmaf(xi, w, o[k]);
    }
  }

  float* orow = out + (size_t)dst[e] * 576;
  atomicAdd(&orow[lane], o[0]);
#pragma unroll
  for (int t = 0; t < 3; t++) atomicAdd(&orow[64 + 3*lane + t], o[1 + t]);
#pragma unroll
  for (int t = 0; t < 5; t++) atomicAdd(&orow[256 + 5*lane + t], o[4 + t]);
}

// ============================================================
extern "C" void kernel_launch(void* const* d_in, const int* in_sizes, int n_in,
                              void* d_out, int out_size, void* d_ws, size_t ws_size,
                              hipStream_t stream)
{
  const float* x  = (const float*)d_in[0];
  const float* sh = (const float*)d_in[1];
  const int* src  = (const int*)d_in[2];
  const int* dst  = (const int*)d_in[3];
  float* out = (float*)d_out;

  const int N = in_sizes[0] / 576;
  const int E = in_sizes[2];

  // layout (u32 units):
  // Tw[1024] | cnt[N] | strt[N+1] | pos[E] | esrc[E] | xb[288N] | sh_r[12E]
  const size_t o_cnt  = 1024;
  const size_t o_strt = o_cnt + (size_t)N;
  const size_t o_pos  = o_strt + (size_t)N + 1;
  const size_t o_esrc = o_pos + (size_t)E;
  size_t o_xb   = o_esrc + (size_t)E;
  o_xb = (o_xb + 3) & ~(size_t)3;
  size_t o_shr  = o_xb + (size_t)288 * N;
  o_shr = (o_shr + 3) & ~(size_t)3;            // 16B-align sh rows
  const size_t need = (o_shr + (size_t)12 * E) * 4;

  float* Tw = (float*)d_ws;
  gen_T_kernel<<<3, 256, 0, stream>>>(Tw);

  if (ws_size >= need){
    int* cnt    = (int*)d_ws + o_cnt;
    int* strt   = (int*)d_ws + o_strt;
    int* pos    = (int*)d_ws + o_pos;
    int* esrc   = (int*)d_ws + o_esrc;
    u16t* xb    = (u16t*)((uint32*)d_ws + o_xb);
    float* sh_r = (float*)((uint32*)d_ws + o_shr);

    const int n4 = (int)(((size_t)N * 576) / 4);
    x2b_kernel<<<(n4 + 255) / 256, 256, 0, stream>>>(x, xb, n4);
    hipMemsetAsync(cnt, 0, (size_t)N * 4, stream);
    hist_kernel<<<(E + 255) / 256, 256, 0, stream>>>(dst, cnt, pos, E);
    scan_kernel<<<1, 1024, 0, stream>>>(cnt, strt, N);
    fill_kernel<<<(E + 255) / 256, 256, 0, stream>>>(dst, src, sh, strt, pos, esrc, sh_r, E);
    tp_fused<<<(N + 3) / 4, 256, 0, stream>>>(xb, sh_r, esrc, strt, Tw, out, N);
  } else {
    hipMemsetAsync(out, 0, (size_t)out_size * 4, stream);
    tp_edge_atomic<<<(E + 3) / 4, 256, 0, stream>>>(x, sh, src, dst, Tw, out, E);
  }
}

// Round 7
// 180.889 us; speedup vs baseline: 1.9910x; 1.0818x over previous
//
#include <hip/hip_runtime.h>

typedef unsigned int uint32;
typedef unsigned short u16t;

// ============================================================
// Compile-time reproduction of np.random.RandomState(0).randn
// (MT19937 + polar Box-Muller). Exact integer/IEEE-double control
// flow -> constexpr-safe; only log/sqrt evaluated on device.
// ============================================================
struct MTS { unsigned int mt[624]; int mti; };

constexpr unsigned int mt_next(MTS& s){
  if (s.mti >= 624){
    for (int i = 0; i < 624; i++){
      unsigned int y = (s.mt[i] & 0x80000000u) | (s.mt[(i+1)%624] & 0x7fffffffu);
      unsigned int v = s.mt[(i+397)%624] ^ (y >> 1);
      if (y & 1u) v ^= 2567483615u;
      s.mt[i] = v;
    }
    s.mti = 0;
  }
  unsigned int y = s.mt[s.mti]; s.mti++;
  y ^= y >> 11;
  y ^= (y << 7)  & 2636928640u;
  y ^= (y << 15) & 4022730752u;
  y ^= y >> 18;
  return y;
}
constexpr double mt_dbl(MTS& s){
  unsigned int a = mt_next(s) >> 5;
  unsigned int b = mt_next(s) >> 6;
  return ((double)a * 67108864.0 + (double)b) / 9007199254740992.0;
}

constexpr int NPAIR = 308;
struct GenData {
  double r2[NPAIR], x1[NPAIR], x2[NPAIR];
  int g_of_t[729];
};

constexpr GenData make_gen(){
  GenData g{};
  for (int i = 0; i < 729; i++) g.g_of_t[i] = -1;
  MTS s{};
  {
    unsigned int sd = 0u;
    for (int p = 0; p < 624; p++){
      s.mt[p] = sd;
      sd = 1812433253u * (sd ^ (sd >> 30)) + (unsigned)p + 1u;
    }
    s.mti = 624;
  }
  for (int p = 0; p < NPAIR; p++){
    double a = 0.0, b = 0.0, r = 0.0;
    do {
      a = 2.0 * mt_dbl(s) - 1.0;
      b = 2.0 * mt_dbl(s) - 1.0;
      r = a*a + b*b;
    } while (r >= 1.0 || r == 0.0);
    g.r2[p] = r; g.x1[p] = a; g.x2[p] = b;
  }
  const int L1[15] = {0,0,0,1,1,1,1,1,1,2,2,2,2,2,2};
  const int L2[15] = {0,1,2,0,1,1,1,2,2,0,1,1,2,2,2};
  const int L3[15] = {0,1,2,1,0,1,2,1,2,2,1,2,0,1,2};
  const int OFF[3] = {0,1,4};
  int gi = 0;
  for (int p = 0; p < 15; p++){
    int d1 = 2*L1[p]+1, d2 = 2*L2[p]+1, d3 = 2*L3[p]+1;
    for (int i = 0; i < d1; i++)
      for (int j = 0; j < d2; j++)
        for (int k = 0; k < d3; k++)
          g.g_of_t[(OFF[L1[p]]+i)*81 + (OFF[L2[p]]+j)*9 + (OFF[L3[p]]+k)] = gi++;
  }
  return g;
}

constexpr GenData h_gd = make_gen();
__constant__ GenData c_gd = h_gd;

__global__ void gen_T_kernel(float* __restrict__ T){
  int t = blockIdx.x * blockDim.x + threadIdx.x;
  if (t >= 729) return;
  int gi = c_gd.g_of_t[t];
  float v = 0.f;
  if (gi >= 0){
    int p = gi >> 1;
    double r2 = c_gd.r2[p];
    double f  = sqrt(-2.0 * log(r2) / r2);
    double xx = (gi & 1) ? c_gd.x1[p] : c_gd.x2[p];
    v = (float)((f * xx) / 3.0);
  }
  T[t] = v;
}

// ---- fp32 -> bf16 (RNE) ----
__device__ __forceinline__ u16t f2b(float f){
  uint32 u = __float_as_uint(f);
  u += 0x7fffu + ((u >> 16) & 1u);
  return (u16t)(u >> 16);
}

// ============================================================
// x repack: channel-major row (576 f32) -> per-channel packed
// bf16 rows of 10 ushorts (20B, 4B-aligned). One thread per
// (node, channel); wave writes 1280B contiguous per node.
// ============================================================
__global__ __launch_bounds__(256) void xrepack_kernel(const float* __restrict__ x,
                                                      uint32* __restrict__ xb2, int N){
  int t = blockIdx.x * 256 + threadIdx.x;
  if (t >= N * 64) return;
  const int n = t >> 6, c = t & 63;
  const float* xr = x + (size_t)n * 576;
  float v[9];
  v[0] = xr[c];
#pragma unroll
  for (int q = 0; q < 3; q++) v[1 + q] = xr[64 + 3*c + q];
#pragma unroll
  for (int q = 0; q < 5; q++) v[4 + q] = xr[256 + 5*c + q];
  uint32* d = xb2 + (size_t)n * 320 + c * 5;
  d[0] = (uint32)f2b(v[0]) | ((uint32)f2b(v[1]) << 16);
  d[1] = (uint32)f2b(v[2]) | ((uint32)f2b(v[3]) << 16);
  d[2] = (uint32)f2b(v[4]) | ((uint32)f2b(v[5]) << 16);
  d[3] = (uint32)f2b(v[6]) | ((uint32)f2b(v[7]) << 16);
  d[4] = (uint32)f2b(v[8]);
}

// ============================================================
// CSR-by-dst: hist -> scan -> fill (epair = {src, e}, 8B)
// ============================================================
__global__ __launch_bounds__(256) void hist_kernel(const int* __restrict__ dst,
                                                   int* __restrict__ cnt,
                                                   int* __restrict__ pos, int E){
  int e = blockIdx.x * 256 + threadIdx.x;
  if (e < E) pos[e] = atomicAdd(&cnt[dst[e]], 1);
}

__global__ void scan_kernel(const int* __restrict__ cnt, int* __restrict__ start, int n){
  __shared__ int part[1024];
  int t = threadIdx.x;
  int ch = (n + 1023) >> 10;
  int b0 = t * ch;
  int sum = 0;
  for (int j = 0; j < ch; j++){ int i = b0 + j; if (i < n) sum += cnt[i]; }
  part[t] = sum;
  __syncthreads();
  for (int off = 1; off < 1024; off <<= 1){
    int v = 0;
    if (t >= off) v = part[t - off];
    __syncthreads();
    part[t] += v;
    __syncthreads();
  }
  int run = (t > 0) ? part[t-1] : 0;
  for (int j = 0; j < ch; j++){
    int i = b0 + j;
    if (i < n){ start[i] = run; run += cnt[i]; }
  }
  if (t == 1023) start[n] = part[1023];
}

__global__ __launch_bounds__(256) void fill_kernel(const int* __restrict__ dst,
                                                   const int* __restrict__ src,
                                                   const int* __restrict__ start,
                                                   const int* __restrict__ pos,
                                                   uint2* __restrict__ epair, int E){
  int e = blockIdx.x * 256 + threadIdx.x;
  if (e >= E) return;
  int p = start[dst[e]] + pos[e];
  epair[p] = make_uint2((uint32)src[e], (uint32)e);
}

// ============================================================
// Fused TP kernel: one wave per node, lane = channel (64).
// Software-pipelined: epair prefetched 2 deep; x (2 loads/lane)
// and sh (9 wave-uniform loads) prefetched 1 deep. W built in
// registers, broadcast via flat LDS (2 writes + 21 b128 reads).
// ============================================================
__global__ __launch_bounds__(256) void tp_fused(
    const uint32* __restrict__ xb2, const float* __restrict__ sh,
    const uint2* __restrict__ epair, const int* __restrict__ starts,
    const float* __restrict__ Tg, float* __restrict__ out, int n_nodes)
{
  __shared__ __align__(16) float Wl[4][88];   // flat 81 (+pad) per wave

  const int wv = threadIdx.x >> 6;
  const int lane = threadIdx.x & 63;
  const int node = blockIdx.x * 4 + wv;
  if (node >= n_nodes) return;

  // per-lane constant T fragments (entry t = i*9+k; lane owns t=lane, t=64+lane)
  const int i0 = lane / 9, k0 = lane % 9;
  const bool has1 = (lane < 17);
  const int e1 = has1 ? (64 + lane) : 63;
  const int i1 = e1 / 9, k1 = e1 % 9;
  float t0[9], t1[9];
#pragma unroll
  for (int j = 0; j < 9; j++){
    t0[j] = Tg[i0*81 + j*9 + k0];
    t1[j] = Tg[i1*81 + j*9 + k1];
  }

  float acc[9];
#pragma unroll
  for (int k = 0; k < 9; k++) acc[k] = 0.f;

  const int s0 = __builtin_amdgcn_readfirstlane(starts[node]);
  const int s1 = __builtin_amdgcn_readfirstlane(starts[node + 1]);
  float* Wp = Wl[wv];

  if (s0 < s1){
    const int last = s1 - 1;
    // prologue: edge s0 fully, edge s0+1's pair
    uint2 pc = epair[s0];
    int sn_c = __builtin_amdgcn_readfirstlane((int)pc.x);
    int ec   = __builtin_amdgcn_readfirstlane((int)pc.y);
    uint2 pnv = epair[(s0 + 1 <= last) ? (s0 + 1) : last];
    int sn_n = __builtin_amdgcn_readfirstlane((int)pnv.x);
    int en   = __builtin_amdgcn_readfirstlane((int)pnv.y);

    // current edge's x (2 loads) and sh (9 wave-uniform loads)
    uint4 xa4; uint32 xa1;
    {
      const uint32* xp = xb2 + (size_t)sn_c * 320 + lane * 5;
      xa4 = *reinterpret_cast<const uint4*>(xp);
      xa1 = xp[4];
    }
    float sva[9];
    {
      const float* sp = sh + (size_t)ec * 9;
#pragma unroll
      for (int j = 0; j < 9; j++) sva[j] = sp[j];
    }

    for (int idx = s0; idx < s1; ++idx){
      // ---- prefetch pair 2 ahead
      const int n2 = (idx + 2 <= last) ? (idx + 2) : last;
      uint2 p2 = epair[n2];
      const int sn_n2 = __builtin_amdgcn_readfirstlane((int)p2.x);
      const int en2   = __builtin_amdgcn_readfirstlane((int)p2.y);

      // ---- issue NEXT edge's x + sh loads (sn_n/en already resident)
      uint4 xb4; uint32 xb1;
      {
        const uint32* xp = xb2 + (size_t)sn_n * 320 + lane * 5;
        xb4 = *reinterpret_cast<const uint4*>(xp);
        xb1 = xp[4];
      }
      float svb[9];
      {
        const float* sp = sh + (size_t)en * 9;
#pragma unroll
        for (int j = 0; j < 9; j++) svb[j] = sp[j];
      }

      // ---- W build in registers (current edge's sh)
      float w0 = 0.f, w1 = 0.f;
#pragma unroll
      for (int j = 0; j < 9; j++){ w0 = fmaf(sva[j], t0[j], w0); w1 = fmaf(sva[j], t1[j], w1); }

      // ---- broadcast via flat LDS
      Wp[lane] = w0;
      if (has1) Wp[64 + lane] = w1;
      asm volatile("s_waitcnt lgkmcnt(0)" ::: "memory");  // W visible wave-wide

      // ---- unpack current x (bf16 pairs -> f32)
      float xv[9];
      xv[0] = __uint_as_float(xa4.x << 16);
      xv[1] = __uint_as_float(xa4.x & 0xffff0000u);
      xv[2] = __uint_as_float(xa4.y << 16);
      xv[3] = __uint_as_float(xa4.y & 0xffff0000u);
      xv[4] = __uint_as_float(xa4.z << 16);
      xv[5] = __uint_as_float(xa4.z & 0xffff0000u);
      xv[6] = __uint_as_float(xa4.w << 16);
      xv[7] = __uint_as_float(xa4.w & 0xffff0000u);
      xv[8] = __uint_as_float(xa1 << 16);

      // ---- matvec: acc[k] += xv[i] * W[i*9+k]  (21 broadcast b128 reads)
      float4 W4[21];
#pragma unroll
      for (int q = 0; q < 21; q++) W4[q] = reinterpret_cast<const float4*>(Wp)[q];
#pragma unroll
      for (int i = 0; i < 9; i++){
        const float xi = xv[i];
#pragma unroll
        for (int k = 0; k < 9; k++){
          const int t = i*9 + k;
          const float w = reinterpret_cast<const float*>(&W4[t >> 2])[t & 3];
          acc[k] = fmaf(xi, w, acc[k]);
        }
      }
      asm volatile("" ::: "memory");  // next iter's LDS writes stay after these reads

      // ---- rotate pipeline regs
      xa4 = xb4; xa1 = xb1;
#pragma unroll
      for (int j = 0; j < 9; j++) sva[j] = svb[j];
      sn_c = sn_n; ec = en;
      sn_n = sn_n2; en = en2;
    }
  }

  float* orow = out + (size_t)node * 576;
  orow[lane] = acc[0];
#pragma unroll
  for (int t = 0; t < 3; t++) orow[64 + 3*lane + t] = acc[1 + t];
#pragma unroll
  for (int t = 0; t < 5; t++) orow[256 + 5*lane + t] = acc[4 + t];
}

// ============================================================
// Last-resort fallback: edge-parallel with atomics (readlane bcast)
// ============================================================
__device__ __forceinline__ float bcast_lane(float v, int lane){
  return __uint_as_float(__builtin_amdgcn_readlane(__float_as_uint(v), lane));
}

__global__ __launch_bounds__(256) void tp_edge_atomic(
    const float* __restrict__ x, const float* __restrict__ sh,
    const int* __restrict__ src, const int* __restrict__ dst,
    const float* __restrict__ Tg, float* __restrict__ out, int E)
{
  const int wv = threadIdx.x >> 6;
  const int lane = threadIdx.x & 63;
  const int e = blockIdx.x * 4 + wv;
  if (e >= E) return;

  const int i0 = lane / 9, k0 = lane % 9;
  const bool has1 = (lane < 17);
  const int e1 = has1 ? (64 + lane) : 63;
  const int i1 = e1 / 9, k1 = e1 % 9;
  float t0[9], t1[9];
#pragma unroll
  for (int j = 0; j < 9; j++){
    t0[j] = Tg[i0*81 + j*9 + k0];
    t1[j] = Tg[i1*81 + j*9 + k1];
  }

  const int sn = src[e];
  const float* she = sh + (size_t)e * 9;
  float sv[9];
#pragma unroll
  for (int j = 0; j < 9; j++) sv[j] = she[j];

  float w0 = 0.f, w1 = 0.f;
#pragma unroll
  for (int j = 0; j < 9; j++) w0 = fmaf(sv[j], t0[j], w0);
#pragma unroll
  for (int j = 0; j < 9; j++) w1 = fmaf(sv[j], t1[j], w1);

  const float* xr = x + (size_t)sn * 576;
  float xv[9];
  xv[0] = xr[lane];
#pragma unroll
  for (int t = 0; t < 3; t++) xv[1 + t] = xr[64 + 3*lane + t];
#pragma unroll
  for (int t = 0; t < 5; t++) xv[4 + t] = xr[256 + 5*lane + t];

  float o[9];
#pragma unroll
  for (int k = 0; k < 9; k++) o[k] = 0.f;
#pragma unroll
  for (int i = 0; i < 9; i++){
    const float xi = xv[i];
#pragma unroll
    for (int k = 0; k < 9; k++){
      const int t = i*9 + k;
      const float w = (t < 64) ? bcast_lane(w0, t) : bcast_lane(w1, t - 64);
      o[k] = fmaf(xi, w, o[k]);
    }
  }

  float* orow = out + (size_t)dst[e] * 576;
  atomicAdd(&orow[lane], o[0]);
#pragma unroll
  for (int t = 0; t < 3; t++) atomicAdd(&orow[64 + 3*lane + t], o[1 + t]);
#pragma unroll
  for (int t = 0; t < 5; t++) atomicAdd(&orow[256 + 5*lane + t], o[4 + t]);
}

// ============================================================
extern "C" void kernel_launch(void* const* d_in, const int* in_sizes, int n_in,
                              void* d_out, int out_size, void* d_ws, size_t ws_size,
                              hipStream_t stream)
{
  const float* x  = (const float*)d_in[0];
  const float* sh = (const float*)d_in[1];
  const int* src  = (const int*)d_in[2];
  const int* dst  = (const int*)d_in[3];
  float* out = (float*)d_out;

  const int N = in_sizes[0] / 576;
  const int E = in_sizes[2];

  // layout (u32 units):
  // Tw[1024] | cnt[N] | strt[N+1] | pos[E] | epair[2E] | xb2[320N]
  const size_t o_cnt  = 1024;
  const size_t o_strt = o_cnt + (size_t)N;
  const size_t o_pos  = o_strt + (size_t)N + 1;
  size_t o_ep   = o_pos + (size_t)E;
  o_ep = (o_ep + 1) & ~(size_t)1;              // 8B-align epair
  size_t o_xb   = o_ep + (size_t)2 * E;
  o_xb = (o_xb + 3) & ~(size_t)3;              // 16B-align xb2
  const size_t need = (o_xb + (size_t)320 * N) * 4;

  float* Tw = (float*)d_ws;
  gen_T_kernel<<<3, 256, 0, stream>>>(Tw);

  if (ws_size >= need){
    int* cnt    = (int*)d_ws + o_cnt;
    int* strt   = (int*)d_ws + o_strt;
    int* pos    = (int*)d_ws + o_pos;
    uint2* ep   = (uint2*)((uint32*)d_ws + o_ep);
    uint32* xb2 = (uint32*)d_ws + o_xb;

    xrepack_kernel<<<(N * 64 + 255) / 256, 256, 0, stream>>>(x, xb2, N);
    hipMemsetAsync(cnt, 0, (size_t)N * 4, stream);
    hist_kernel<<<(E + 255) / 256, 256, 0, stream>>>(dst, cnt, pos, E);
    scan_kernel<<<1, 1024, 0, stream>>>(cnt, strt, N);
    fill_kernel<<<(E + 255) / 256, 256, 0, stream>>>(dst, src, strt, pos, ep, E);
    tp_fused<<<(N + 3) / 4, 256, 0, stream>>>(xb2, sh, ep, strt, Tw, out, N);
  } else {
    hipMemsetAsync(out, 0, (size_t)out_size * 4, stream);
    tp_edge_atomic<<<(E + 3) / 4, 256, 0, stream>>>(x, sh, src, dst, Tw, out, E);
  }
}